// Round 11
// baseline (120.428 us; speedup 1.0000x reference)
//
#include <hip/hip_runtime.h>

// SSIM, fused separable, v9: ROLLED 2-row loop + register-rotated ring.
// R4-R10 post-mortem: runtime == blocks/CU x block-duration in every fully
// unrolled variant (~90KB bodies) -> I-cache thrash serializes blocks; R1's
// small rolled loops got near-full residency. This version keeps R10's
// pipeline (global_load_lds pair staging, triple pair-buffer, counted
// vmcnt(4), masked Wp windows, 4-quantity V-ring) but the main loop body is
// ONE 2-row iteration (~3KB): ring slots stay compile-time via an explicit
// rotate-by-2 (44 v_movs / 2 rows), LDS pair-buffers rotate as 3 pointers.

#define IMG_H 512
#define IMG_W 512
#define N_PLANES 48
#define KW 11
#define BLOCK 256
#define WAVE_COLS 64
#define STRIP_H 64
#define BLOCKS_X (IMG_W / (WAVE_COLS * 4))            // 2
#define BLOCKS_Y (IMG_H / STRIP_H)                    // 8
#define NBLK (N_PLANES * BLOCKS_X * BLOCKS_Y)         // 768
#define PAIRF 320          // floats per pair-buf: row0[img1 80|img2 80] row1[..]
#define C1_CONST 1.0e-4f
#define C2_CONST 9.0e-4f

typedef const __attribute__((address_space(1))) void GV;
typedef __attribute__((address_space(3))) void LV;

__device__ __forceinline__ void dma16(const float* g, float* l) {
  __builtin_amdgcn_global_load_lds((GV*)g, (LV*)l, 16, 0, 0);
}

__device__ __forceinline__ float bcastf(float x) {
  return __uint_as_float(__builtin_amdgcn_readfirstlane(__float_as_uint(x)));
}

#define TAPX(E, AV, BV) { const float w_ = Wp[(E)]; \
    const float t1_ = w_ * (AV); const float t2_ = w_ * (BV); \
    m1_ += t1_; m2_ += t2_; \
    q12_ += t1_ * (BV); qs_ += t1_ * (AV); qs_ += t2_ * (BV); }

// H-pass of one row (zero if ROW outside image) from pair-slot base BP
// (img1 at +0, img2 at +80) into named outputs OM1..OQ12.
#define HPASS2(ROW, BP, OM1, OM2, OQS, OQ12) { \
  float m1_ = 0.f, m2_ = 0.f, qs_ = 0.f, q12_ = 0.f; \
  if ((ROW) >= 0 && (ROW) < IMG_H) { \
    const float* s1_ = (BP); const float* s2_ = (BP) + 80; \
    { const float4 A0 = *(const float4*)(s1_ + a); \
      const float4 A1 = *(const float4*)(s1_ + a + 4); \
      const float4 B0 = *(const float4*)(s2_ + a); \
      const float4 B1 = *(const float4*)(s2_ + a + 4); \
      TAPX(0, A0.x, B0.x) TAPX(1, A0.y, B0.y) TAPX(2, A0.z, B0.z) \
      TAPX(3, A0.w, B0.w) TAPX(4, A1.x, B1.x) TAPX(5, A1.y, B1.y) \
      TAPX(6, A1.z, B1.z) TAPX(7, A1.w, B1.w) } \
    { const float4 A2 = *(const float4*)(s1_ + a + 8); \
      const float2 A3 = *(const float2*)(s1_ + a + 12); \
      const float4 B2 = *(const float4*)(s2_ + a + 8); \
      const float2 B3 = *(const float2*)(s2_ + a + 12); \
      TAPX(8, A2.x, B2.x)  TAPX(9, A2.y, B2.y)  TAPX(10, A2.z, B2.z) \
      TAPX(11, A2.w, B2.w) TAPX(12, A3.x, B3.x) TAPX(13, A3.y, B3.y) } \
  } \
  OM1 = m1_; OM2 = m2_; OQS = qs_; OQ12 = q12_; }

#define EMTV(K, VM1, VM2, VQS, VQ12) { const float w_ = wkr[(K)]; \
    vm1_ += w_ * (VM1); vm2_ += w_ * (VM2); \
    vqs_ += w_ * (VQS); vq12_ += w_ * (VQ12); }

#define EMTS(K, I) EMTV(K, rm1[I], rm2[I], rqs[I], rq12[I])

#define SSIM_ACC { \
  const float mu11_ = vm1_ * vm1_; \
  const float mu22_ = vm2_ * vm2_; \
  const float mu12_ = vm1_ * vm2_; \
  const float musum_ = mu11_ + mu22_; \
  const float sigs_  = vqs_  - musum_; \
  const float sig12_ = vq12_ - mu12_; \
  const float num_ = (2.f * mu12_ + C1_CONST) * (2.f * sig12_ + C2_CONST); \
  const float den_ = (musum_ + C1_CONST) * (sigs_ + C2_CONST); \
  acc += num_ * __builtin_amdgcn_rcpf(den_); }

// One 2-row iteration. Invariant at top: rm*[i] = H(gr-11+i), i=0..10;
// pair (gr,gr+1) staged in b0 (DMA complete after vmcnt(4)); pair
// (gr+2,gr+3) in flight into b1.
// 1) issue DMA pair (gr+4,gr+5) -> b2
// 2) vmcnt(4): waits only for b0's pair (issued 2 iterations ago)
// 3) t = H(gr), u = H(gr+1) from b0
// 4) if EMIT: rows gr-5 (taps rm[1..10],t) and gr-4 (rm[2..10],t,u)
// 5) rotate ring by 2; rotate buffer pointers
#define ITER(DOEMIT) { \
  { const int na_ = gr+4 < 0 ? 0 : (gr+4 > IMG_H-1 ? IMG_H-1 : gr+4); \
    const int nb_ = gr+5 < 0 ? 0 : (gr+5 > IMG_H-1 ? IMG_H-1 : gr+5); \
    if (lane < 40) { \
      dma16(srcbase + (size_t)na_ * IMG_W, b2); \
      dma16(srcbase + (size_t)nb_ * IMG_W, b2 + 160); } } \
  asm volatile("s_waitcnt vmcnt(4)" ::: "memory"); \
  __builtin_amdgcn_sched_barrier(0); \
  float tm1, tm2, tqs, tq12, um1, um2, uqs, uq12; \
  HPASS2(gr,     b0,       tm1, tm2, tqs, tq12) \
  HPASS2(gr + 1, b0 + 160, um1, um2, uqs, uq12) \
  if (DOEMIT) { \
    { float vm1_ = 0.f, vm2_ = 0.f, vqs_ = 0.f, vq12_ = 0.f; \
      EMTS(0,1) EMTS(1,2) EMTS(2,3) EMTS(3,4) EMTS(4,5) EMTS(5,6) \
      EMTS(6,7) EMTS(7,8) EMTS(8,9) EMTS(9,10) \
      EMTV(10, tm1, tm2, tqs, tq12) \
      SSIM_ACC } \
    { float vm1_ = 0.f, vm2_ = 0.f, vqs_ = 0.f, vq12_ = 0.f; \
      EMTS(0,2) EMTS(1,3) EMTS(2,4) EMTS(3,5) EMTS(4,6) EMTS(5,7) \
      EMTS(6,8) EMTS(7,9) EMTS(8,10) \
      EMTV(9,  tm1, tm2, tqs, tq12) \
      EMTV(10, um1, um2, uqs, uq12) \
      SSIM_ACC } \
  } \
  _Pragma("unroll") \
  for (int i_ = 0; i_ < 9; ++i_) { \
    rm1[i_] = rm1[i_+2]; rm2[i_] = rm2[i_+2]; \
    rqs[i_] = rqs[i_+2]; rq12[i_] = rq12[i_+2]; } \
  rm1[9]  = tm1; rm2[9]  = tm2; rqs[9]  = tqs; rq12[9]  = tq12; \
  rm1[10] = um1; rm2[10] = um2; rqs[10] = uqs; rq12[10] = uq12; \
  { float* tb_ = b0; b0 = b1; b1 = b2; b2 = tb_; } \
  gr += 2; }

__global__ __launch_bounds__(BLOCK) void ssim_strip_kernel(
    const float* __restrict__ img1,
    const float* __restrict__ img2,
    const float* __restrict__ kern2d,
    float* __restrict__ partial)
{
  // Wave-private triple pair-buffers: [wave][buf3][pair 320]. 15,360 B.
  __shared__ __align__(16) float slice[4][3][PAIRF];
  __shared__ float wk_lds[KW];
  __shared__ float wave_sums[BLOCK / 64];

  const int tid  = threadIdx.x;
  const int wid  = tid >> 6;
  const int lane = tid & 63;

  // 1D kernel = row sums of the normalized 2D kernel (== normalized 1D Gaussian).
  if (tid < KW) {
    float s = 0.f;
    #pragma unroll
    for (int j = 0; j < KW; ++j) s += kern2d[tid * KW + j];
    wk_lds[tid] = s;
  }
  __syncthreads();

  // V-pass weights, wave-uniform (SGPRs).
  float wkr[KW];
  #pragma unroll
  for (int k = 0; k < KW; ++k) wkr[k] = bcastf(wk_lds[k]);

  const int bid   = blockIdx.x;
  const int plane = bid / (BLOCKS_X * BLOCKS_Y);
  const int srem  = bid % (BLOCKS_X * BLOCKS_Y);
  const int y0    = (srem / BLOCKS_X) * STRIP_H;
  const int x0b   = (srem % BLOCKS_X) * (WAVE_COLS * 4);
  const float* __restrict__ p1 = img1 + (size_t)plane * IMG_H * IMG_W;
  const float* __restrict__ p2 = img2 + (size_t)plane * IMG_H * IMG_W;

  const int x0w   = x0b + wid * WAVE_COLS;   // wave's first column
  const int gx    = x0w + lane;              // this thread's output column
  const int wbase = x0w - 8;                 // slice float 0 <-> global col wbase

  // Lane's window: slice floats [a, a+13]; taps at e in [r, r+10].
  const int a = (lane + 3) & ~3;
  const int r = (lane + 3) & 3;

  float Wp[14];
  #pragma unroll
  for (int e = 0; e < 14; ++e) {
    const int k   = e - r;
    const int col = wbase + a + e;
    Wp[e] = (k >= 0 && k <= 10 && col >= 0 && col < IMG_W) ? wk_lds[k] : 0.f;
  }

  // DMA source: lanes 0..19 cover img1 floats 4l..4l+3 of the 80-float span,
  // lanes 20..39 cover img2 (landing at +80 via dest = base + lane*16).
  // wbase % 4 == 0, IMG_W % 4 == 0: each 4-float group entirely in- or
  // out-of-image; clamped addresses affect only fully-OOB groups (Wp-zeroed).
  const int li  = lane < 20 ? lane : lane - 20;
  const int c0r = wbase + 4 * li;
  const int c0  = c0r < 0 ? 0 : (c0r > IMG_W - 4 ? IMG_W - 4 : c0r);
  const float* srcbase = (lane < 20 ? p1 : p2) + c0;

  float* b0 = &slice[wid][0][0];
  float* b1 = &slice[wid][1][0];
  float* b2 = &slice[wid][2][0];

  float rm1[11], rm2[11], rqs[11], rq12[11];
  #pragma unroll
  for (int i = 0; i < 11; ++i) { rm1[i]=0.f; rm2[i]=0.f; rqs[i]=0.f; rq12[i]=0.f; }
  float acc = 0.f;
  int gr = y0 - 5;

  // Prologue: stage pairs (gr,gr+1)->b0 and (gr+2,gr+3)->b1, oldest first.
  {
    const int q0 = gr     < 0 ? 0 : gr;
    const int q1 = gr + 1 < 0 ? 0 : gr + 1;
    const int q2 = gr + 2 < 0 ? 0 : gr + 2;
    const int q3 = gr + 3 < 0 ? 0 : gr + 3;
    if (lane < 40) {
      dma16(srcbase + (size_t)q0 * IMG_W, b0);
      dma16(srcbase + (size_t)q1 * IMG_W, b0 + 160);
      dma16(srcbase + (size_t)q2 * IMG_W, b1);
      dma16(srcbase + (size_t)q3 * IMG_W, b1 + 160);
    }
  }

  // 5 warmup iterations (fill ring), then 32 emitting iterations (64 rows).
  #pragma unroll 1
  for (int it = 0; it < 5; ++it) { ITER(0) }
  #pragma unroll 1
  for (int it = 0; it < 32; ++it) { ITER(1) }

  // Block reduction.
  #pragma unroll
  for (int off = 32; off > 0; off >>= 1)
    acc += __shfl_down(acc, off, 64);
  if ((tid & 63) == 0) wave_sums[tid >> 6] = acc;
  __syncthreads();
  if (tid == 0)
    partial[bid] = wave_sums[0] + wave_sums[1] + wave_sums[2] + wave_sums[3];
}

__global__ __launch_bounds__(256) void ssim_reduce_kernel(
    const float* __restrict__ partial, float* __restrict__ out)
{
  const int tid = threadIdx.x;
  double acc = 0.0;
  for (int i = tid; i < NBLK; i += 256) acc += (double)partial[i];
  #pragma unroll
  for (int off = 32; off > 0; off >>= 1)
    acc += __shfl_down(acc, off, 64);
  __shared__ double wsums[4];
  if ((tid & 63) == 0) wsums[tid >> 6] = acc;
  __syncthreads();
  if (tid == 0) {
    const double total = wsums[0] + wsums[1] + wsums[2] + wsums[3];
    const double inv_n = 1.0 / ((double)N_PLANES * IMG_H * IMG_W);
    out[0] = (float)(total * inv_n);
  }
}

extern "C" void kernel_launch(void* const* d_in, const int* in_sizes, int n_in,
                              void* d_out, int out_size, void* d_ws, size_t ws_size,
                              hipStream_t stream)
{
  const float* img1 = (const float*)d_in[0];
  const float* img2 = (const float*)d_in[1];
  const float* kern = (const float*)d_in[2];
  float* out = (float*)d_out;
  float* partial = (float*)d_ws;   // NBLK floats = 3 KiB

  ssim_strip_kernel<<<NBLK, BLOCK, 0, stream>>>(img1, img2, kern, partial);
  ssim_reduce_kernel<<<1, 256, 0, stream>>>(partial, out);
}

// Round 12
// 104.037 us; speedup vs baseline: 1.1576x; 1.1576x over previous
//
#include <hip/hip_runtime.h>

// SSIM, fused separable, v10: ONE WAVE PER BLOCK (64 threads), R10 pipeline.
// R4-R11 invariant: occupancy pinned ~18-21% (~1.5 blocks/CU resident) for
// all multi-wave long-block variants despite VGPR/LDS allowing 4 blocks/CU;
// runtime == blocks/CU x block time. R1 (12288 small blocks) reached 32.5%.
// Probe: waves share nothing -> make each wave its own block (3072 blocks,
// 12/CU dispatched, 3.8KB LDS each). Pipeline unchanged from R10 (best):
// global_load_lds pair staging, triple pair-buffer, vmcnt(4) counted wait,
// masked Wp windows, 4-quantity x 12-slot ring, static phase unroll.

#define IMG_H 512
#define IMG_W 512
#define N_PLANES 48
#define KW 11
#define BLOCK 64
#define WAVE_COLS 64
#define STRIP_H 64
#define COLG 8                                        // 512 / 64
#define BLOCKS_Y (IMG_H / STRIP_H)                    // 8
#define NBLK (N_PLANES * COLG * BLOCKS_Y)             // 3072
#define PAIRF 320          // floats per pair-buf: row0[img1 80|img2 80] row1[..]
#define C1_CONST 1.0e-4f
#define C2_CONST 9.0e-4f

typedef const __attribute__((address_space(1))) void GV;
typedef __attribute__((address_space(3))) void LV;

__device__ __forceinline__ void dma16(const float* g, float* l) {
  __builtin_amdgcn_global_load_lds((GV*)g, (LV*)l, 16, 0, 0);
}

__device__ __forceinline__ float bcastf(float x) {
  return __uint_as_float(__builtin_amdgcn_readfirstlane(__float_as_uint(x)));
}

#define TAPX(E, AV, BV) { const float w_ = Wp[(E)]; \
    const float t1_ = w_ * (AV); const float t2_ = w_ * (BV); \
    m1_ += t1_; m2_ += t2_; \
    q12_ += t1_ * (BV); qs_ += t1_ * (AV); qs_ += t2_ * (BV); }

// H-pass of one row from slice base BP (img1 at +0, img2 at +80) into ring
// slot SLOT; zeros if ROW outside the image (zero-pad convolution).
#define HPASS(ROW, SLOT, BP) { \
  if ((ROW) >= 0 && (ROW) < IMG_H) { \
    const float* s1_ = (BP); const float* s2_ = (BP) + 80; \
    float m1_ = 0.f, m2_ = 0.f, qs_ = 0.f, q12_ = 0.f; \
    { const float4 A0 = *(const float4*)(s1_ + a); \
      const float4 A1 = *(const float4*)(s1_ + a + 4); \
      const float4 B0 = *(const float4*)(s2_ + a); \
      const float4 B1 = *(const float4*)(s2_ + a + 4); \
      TAPX(0, A0.x, B0.x) TAPX(1, A0.y, B0.y) TAPX(2, A0.z, B0.z) \
      TAPX(3, A0.w, B0.w) TAPX(4, A1.x, B1.x) TAPX(5, A1.y, B1.y) \
      TAPX(6, A1.z, B1.z) TAPX(7, A1.w, B1.w) } \
    { const float4 A2 = *(const float4*)(s1_ + a + 8); \
      const float2 A3 = *(const float2*)(s1_ + a + 12); \
      const float4 B2 = *(const float4*)(s2_ + a + 8); \
      const float2 B3 = *(const float2*)(s2_ + a + 12); \
      TAPX(8, A2.x, B2.x)  TAPX(9, A2.y, B2.y)  TAPX(10, A2.z, B2.z) \
      TAPX(11, A2.w, B2.w) TAPX(12, A3.x, B3.x) TAPX(13, A3.y, B3.y) } \
    rm1[(SLOT)] = m1_; rm2[(SLOT)] = m2_; \
    rqs[(SLOT)] = qs_; rq12[(SLOT)] = q12_; \
  } else { \
    rm1[(SLOT)] = 0.f; rm2[(SLOT)] = 0.f; \
    rqs[(SLOT)] = 0.f; rq12[(SLOT)] = 0.f; } }

#define EMT(K, QQ) { const float w_ = wkr[(K)]; \
    vm1_ += w_ * rm1[(QQ)]; vm2_ += w_ * rm2[(QQ)]; \
    vqs_ += w_ * rqs[(QQ)]; vq12_ += w_ * rq12[(QQ)]; }

// V-pass + SSIM for one output row whose tap-k ring slot is (OFF+K)%12.
#define EMITQ(OFF) { \
  float vm1_ = 0.f, vm2_ = 0.f, vqs_ = 0.f, vq12_ = 0.f; \
  EMT(0, ((OFF)+0)%12)  EMT(1, ((OFF)+1)%12)  EMT(2, ((OFF)+2)%12) \
  EMT(3, ((OFF)+3)%12)  EMT(4, ((OFF)+4)%12)  EMT(5, ((OFF)+5)%12) \
  EMT(6, ((OFF)+6)%12)  EMT(7, ((OFF)+7)%12)  EMT(8, ((OFF)+8)%12) \
  EMT(9, ((OFF)+9)%12)  EMT(10, ((OFF)+10)%12) \
  const float mu11_ = vm1_ * vm1_; \
  const float mu22_ = vm2_ * vm2_; \
  const float mu12_ = vm1_ * vm2_; \
  const float musum_ = mu11_ + mu22_; \
  const float sigs_  = vqs_  - musum_; \
  const float sig12_ = vq12_ - mu12_; \
  const float num_ = (2.f * mu12_ + C1_CONST) * (2.f * sig12_ + C2_CONST); \
  const float den_ = (musum_ + C1_CONST) * (sigs_ + C2_CONST); \
  acc += num_ * __builtin_amdgcn_rcpf(den_); }

// One 2-row step, phase P = step % 6 (compile-time).
// Rows processed: (gr, gr+1); ring slots (2P)%12, (2P+1)%12; buf P%3.
// Issues the pair for step+2 (rows gr+4, gr+5) into buf (P+2)%3, then
// vmcnt(4) waits only for THIS step's pair (issued 2 steps ago).
#define STEP2(P, EMIT) { \
  { const int na_ = gr+4 < 0 ? 0 : (gr+4 > IMG_H-1 ? IMG_H-1 : gr+4); \
    const int nb_ = gr+5 < 0 ? 0 : (gr+5 > IMG_H-1 ? IMG_H-1 : gr+5); \
    if (lane < 40) { \
      float* d_ = slw + (((P)+2)%3) * PAIRF; \
      dma16(srcbase + (size_t)na_ * IMG_W, d_); \
      dma16(srcbase + (size_t)nb_ * IMG_W, d_ + 160); } } \
  asm volatile("s_waitcnt vmcnt(4)" ::: "memory"); \
  __builtin_amdgcn_sched_barrier(0); \
  { const float* bp_ = slw + ((P)%3) * PAIRF; \
    HPASS(gr,     (2*(P))%12,     bp_) \
    HPASS(gr + 1, (2*(P)+1)%12,   bp_ + 160) } \
  if (EMIT) { EMITQ((2*(P)+2)%12) EMITQ((2*(P)+3)%12) } \
  gr += 2; }

__global__ __launch_bounds__(BLOCK) void ssim_strip_kernel(
    const float* __restrict__ img1,
    const float* __restrict__ img2,
    const float* __restrict__ kern2d,
    float* __restrict__ partial)
{
  // Triple pair-buffers for the single wave: [buf3][row2][img2][80]. 3840 B.
  __shared__ __align__(16) float slice[3][2][2][80];
  __shared__ float wk_lds[KW];

  const int lane = threadIdx.x;

  // 1D kernel = row sums of the normalized 2D kernel (== normalized 1D Gaussian).
  if (lane < KW) {
    float s = 0.f;
    #pragma unroll
    for (int j = 0; j < KW; ++j) s += kern2d[lane * KW + j];
    wk_lds[lane] = s;
  }
  __syncthreads();

  // V-pass weights, wave-uniform (SGPRs).
  float wkr[KW];
  #pragma unroll
  for (int k = 0; k < KW; ++k) wkr[k] = bcastf(wk_lds[k]);

  const int bid   = blockIdx.x;
  const int plane = bid / (COLG * BLOCKS_Y);
  const int trem  = bid % (COLG * BLOCKS_Y);
  const int y0    = (trem / COLG) * STRIP_H;
  const int x0w   = (trem % COLG) * WAVE_COLS;
  const float* __restrict__ p1 = img1 + (size_t)plane * IMG_H * IMG_W;
  const float* __restrict__ p2 = img2 + (size_t)plane * IMG_H * IMG_W;

  const int gx    = x0w + lane;              // this thread's output column
  const int wbase = x0w - 8;                 // slice float 0 <-> global col wbase

  // Lane's window: slice floats [a, a+13]; taps at e in [r, r+10].
  const int a = (lane + 3) & ~3;
  const int r = (lane + 3) & 3;

  float Wp[14];
  #pragma unroll
  for (int e = 0; e < 14; ++e) {
    const int k   = e - r;
    const int col = wbase + a + e;
    Wp[e] = (k >= 0 && k <= 10 && col >= 0 && col < IMG_W) ? wk_lds[k] : 0.f;
  }

  // DMA source: lanes 0..19 cover img1 floats 4l..4l+3 of the 80-float span,
  // lanes 20..39 cover img2 (landing at +80 via dest = base + lane*16).
  // wbase % 4 == 0, IMG_W % 4 == 0: each 4-float group entirely in- or
  // out-of-image; clamped addresses affect only fully-OOB groups (Wp-zeroed).
  const int li  = lane < 20 ? lane : lane - 20;
  const int c0r = wbase + 4 * li;
  const int c0  = c0r < 0 ? 0 : (c0r > IMG_W - 4 ? IMG_W - 4 : c0r);
  const float* srcbase = (lane < 20 ? p1 : p2) + c0;

  float* slw = &slice[0][0][0][0];

  float rm1[12], rm2[12], rqs[12], rq12[12];
  float acc = 0.f;
  int gr = y0 - 5;

  // Prologue: stage pairs for steps 0 (buf 0) and 1 (buf 1), oldest first.
  {
    const int q0 = gr     < 0 ? 0 : gr;
    const int q1 = gr + 1 < 0 ? 0 : gr + 1;
    const int q2 = gr + 2 < 0 ? 0 : gr + 2;
    const int q3 = gr + 3 < 0 ? 0 : gr + 3;
    if (lane < 40) {
      dma16(srcbase + (size_t)q0 * IMG_W, slw);
      dma16(srcbase + (size_t)q1 * IMG_W, slw + 160);
      dma16(srcbase + (size_t)q2 * IMG_W, slw + PAIRF);
      dma16(srcbase + (size_t)q3 * IMG_W, slw + PAIRF + 160);
    }
  }

  // 37 steps x 2 rows = 74 rows; steps 0-4 warm up, steps 5-36 emit 2 rows.
  STEP2(0, 0) STEP2(1, 0) STEP2(2, 0) STEP2(3, 0) STEP2(4, 0)
  STEP2(5, 1)
  #pragma unroll 1
  for (int it = 0; it < 5; ++it) {
    STEP2(0, 1) STEP2(1, 1) STEP2(2, 1) STEP2(3, 1) STEP2(4, 1) STEP2(5, 1)
  }
  STEP2(0, 1)

  // Wave reduction.
  #pragma unroll
  for (int off = 32; off > 0; off >>= 1)
    acc += __shfl_down(acc, off, 64);
  if (lane == 0) partial[bid] = acc;
}

__global__ __launch_bounds__(256) void ssim_reduce_kernel(
    const float* __restrict__ partial, float* __restrict__ out)
{
  const int tid = threadIdx.x;
  double acc = 0.0;
  for (int i = tid; i < NBLK; i += 256) acc += (double)partial[i];
  #pragma unroll
  for (int off = 32; off > 0; off >>= 1)
    acc += __shfl_down(acc, off, 64);
  __shared__ double wsums[4];
  if ((tid & 63) == 0) wsums[tid >> 6] = acc;
  __syncthreads();
  if (tid == 0) {
    const double total = wsums[0] + wsums[1] + wsums[2] + wsums[3];
    const double inv_n = 1.0 / ((double)N_PLANES * IMG_H * IMG_W);
    out[0] = (float)(total * inv_n);
  }
}

extern "C" void kernel_launch(void* const* d_in, const int* in_sizes, int n_in,
                              void* d_out, int out_size, void* d_ws, size_t ws_size,
                              hipStream_t stream)
{
  const float* img1 = (const float*)d_in[0];
  const float* img2 = (const float*)d_in[1];
  const float* kern = (const float*)d_in[2];
  float* out = (float*)d_out;
  float* partial = (float*)d_ws;   // NBLK floats = 12 KiB

  ssim_strip_kernel<<<NBLK, BLOCK, 0, stream>>>(img1, img2, kern, partial);
  ssim_reduce_kernel<<<1, 256, 0, stream>>>(partial, out);
}